// Round 7
// baseline (188.229 us; speedup 1.0000x reference)
//
#include <hip/hip_runtime.h>
#include <hip/hip_fp16.h>

#define N_NODES 100000
#define IN_F 128
#define NF 16      // HEADS * OUT_C
#define HEADS 8
#define NEG_SLOPE 0.2f
#define LOG2E 1.44269504f

#define RB 196          // nodes per bin (NON-pow2: NB=511 ~= 2 blocks/CU exactly)
#define NB 511          // ceil(100000/196); 510*196=99960, bin 510 has 40 nodes
#define SBITS 17        // src id bits (100000 < 2^17)
#define SMASK ((1u << SBITS) - 1)
#define BIN_C 4096      // edges per binning block (8/thread @512)
#define CAPB 7040       // per-bin capacity: mean 6272 + 9.7 sigma; rc[7] covers it
#define CUR_STRIDE 16   // bin_cursor padded to 1 per 64B cache line (anti-contention)

// Node record rec[n]: 16 halves = 32B. Table = 3.2 MB -> L2-resident per XCD.

// Transposed-W LDS layout: row j (j = output-pair 0..7) holds K=128 float2
// pairs (W[k][2j], W[k][2j+1]) at float2-stride 130 (1040B rows, 16B-aligned).
// Bank math: lane j reads float4 @ byte 1040*j + 32*k4 -> bank quad (4j)%32,
// all 8 j's distinct -> ZERO bank conflict; 8-lane broadcast per address free.
#define WT_F2_STRIDE 130
#define WT_FLOATS (8 * 2 * WT_F2_STRIDE)   // 2080 floats = 8320 B

// ---------------------------------------------------------------------------
// phase1: h = x@W. 8 lanes per node, each lane computes an output PAIR.
// W transposed in LDS -> 2x ds_read_b128 per 4 k-steps (64 LDS instrs/thread,
// half of the previous 128 ds_read_b64).
// ---------------------------------------------------------------------------
__device__ __forceinline__ void phase1_body(
    int pb, const float* __restrict__ x, const float* __restrict__ W,
    __half* __restrict__ rec, float* Ws)
{
    int t = threadIdx.x;
    // transpose-fill: i = k*8 + j ; Wg2[i] = (W[k][2j], W[k][2j+1])
    const float2* Wg2 = (const float2*)W;
    float2* Ws2 = (float2*)Ws;
    for (int i = t; i < IN_F * 8; i += 512) {
        int k = i >> 3, j = i & 7;
        Ws2[j * WT_F2_STRIDE + k] = Wg2[i];
    }
    __syncthreads();

    int tid  = pb * 512 + t;
    int node = tid >> 3;
    int j    = tid & 7;         // output-pair index (cols 2j, 2j+1)
    if (node >= N_NODES) return;

    const float4* xr4 = (const float4*)(x + (size_t)node * IN_F);
    const float4* Ws4 = (const float4*)Ws;   // row j at float4 index j*65

    int wbase = j * 65;
    float a0 = 0.f, b0 = 0.f, a1 = 0.f, b1 = 0.f;
    #pragma unroll 8
    for (int k4 = 0; k4 < IN_F / 4; ++k4) {
        float4 xv  = xr4[k4];
        float4 w01 = Ws4[wbase + 2 * k4];       // pairs k=4k4, 4k4+1
        float4 w23 = Ws4[wbase + 2 * k4 + 1];   // pairs k=4k4+2, 4k4+3
        a0 = fmaf(xv.x, w01.x, a0); b0 = fmaf(xv.x, w01.y, b0);
        a1 = fmaf(xv.y, w01.z, a1); b1 = fmaf(xv.y, w01.w, b1);
        a0 = fmaf(xv.z, w23.x, a0); b0 = fmaf(xv.z, w23.y, b0);
        a1 = fmaf(xv.w, w23.z, a1); b1 = fmaf(xv.w, w23.w, b1);
    }
    __half2 hv = __floats2half2_rn(a0 + a1, b0 + b1);
    *(__half2*)(rec + (size_t)node * NF + 2 * j) = hv;
}

// ---------------------------------------------------------------------------
// Fused kernel: every 3rd block is bin-role (SB total), rest phase1 (PB).
// Bin role: load 4096 edges into registers; LDS counting-sort by dst bin
// (511 bins of 196 nodes, bin = d/196 via magic-mul); reserve per-(block,bin)
// ranges with one global atomic each (cursors line-padded: 511 distinct 64B
// lines instead of 32 -> no same-line atomic serialization across 782 blocks);
// write packed (d_local<<17 | src).
// ---------------------------------------------------------------------------
__global__ __launch_bounds__(512) void fused_p1_bin(
    const int* __restrict__ ei, int* __restrict__ bin_cursor,
    unsigned* __restrict__ bins,
    const float* __restrict__ x, const float* __restrict__ W,
    __half* __restrict__ rec, int E, int SB)
{
    __shared__ union {
        struct {
            unsigned staging[BIN_C];        // 16 KB
            unsigned short bin16[BIN_C];    // 8 KB
            int hist[NB], offs[NB], cur[NB], gbase[NB]; // 8.2 KB
            int wsum[8], woff[8];
        } b;
        float Ws[WT_FLOATS];                // 8.3 KB (transposed W)
    } sm;

    int idx = blockIdx.x;
    bool is_bin = (idx % 3 == 0) && (idx / 3 < SB);
    if (!is_bin) {
        int cb = (idx + 2) / 3; if (cb > SB) cb = SB;
        phase1_body(idx - cb, x, W, rec, sm.Ws);
        return;
    }

    int t = threadIdx.x;
    int base = (idx / 3) * BIN_C;
    int n_valid = E - base;
    if (n_valid > BIN_C) n_valid = BIN_C;
    if (n_valid < 0) n_valid = 0;

    // load this block's edges once, coalesced, into registers
    int es[8], ed[8];
    #pragma unroll
    for (int k = 0; k < 8; ++k) {
        int i = t + 512 * k;
        bool v = i < n_valid;
        es[k] = v ? ei[base + i] : 0;
        ed[k] = v ? ei[E + base + i] : -1;
    }

    if (t < NB) sm.b.hist[t] = 0;
    __syncthreads();

    // A: histogram of dst bins (from registers); bin = d/196 (magic-mul)
    #pragma unroll
    for (int k = 0; k < 8; ++k)
        if (ed[k] >= 0) atomicAdd(&sm.b.hist[(unsigned)ed[k] / RB], 1);
    __syncthreads();

    // B: block-wide exclusive scan of hist (1 bin/thread) + global reserve
    int sum = (t < NB) ? sm.b.hist[t] : 0;
    int lane = t & 63, wid = t >> 6;
    int v = sum;
    #pragma unroll
    for (int o = 1; o < 64; o <<= 1) {
        int u = __shfl_up(v, o);
        if (lane >= o) v += u;
    }
    if (lane == 63) sm.b.wsum[wid] = v;
    __syncthreads();
    if (t == 0) { int r = 0; for (int w = 0; w < 8; ++w) { sm.b.woff[w] = r; r += sm.b.wsum[w]; } }
    __syncthreads();
    int run = sm.b.woff[wid] + v - sum;
    if (t < NB) { sm.b.offs[t] = run; sm.b.cur[t] = run; }
    __syncthreads();
    if (t < NB)
        sm.b.gbase[t] = sm.b.hist[t] ? atomicAdd(&bin_cursor[t * CUR_STRIDE], sm.b.hist[t]) : 0;
    __syncthreads();

    // C: counting-sort into LDS staging (from registers)
    #pragma unroll
    for (int k = 0; k < 8; ++k) {
        if (ed[k] >= 0) {
            unsigned d = (unsigned)ed[k];
            unsigned bb = d / RB;
            unsigned dl = d - bb * RB;          // local node id, 0..195
            int slot = atomicAdd(&sm.b.cur[bb], 1);
            sm.b.staging[slot] = (dl << SBITS) | (unsigned)es[k];
            sm.b.bin16[slot] = (unsigned short)bb;
        }
    }
    __syncthreads();

    // D: coalesced write-out (runs of ~8 consecutive slots per bin)
    for (int i = t; i < n_valid; i += 512) {
        int b = sm.b.bin16[i];
        int pos = sm.b.gbase[b] + (i - sm.b.offs[b]);
        if (pos < CAPB) bins[(size_t)b * CAPB + pos] = sm.b.staging[i];
    }
}

// ---------------------------------------------------------------------------
// Accum: ONE 1024-thread block per 196-node bin, grid 511 = 255 CUs x 2 + 1
// -> ~100% CU balance. Phases A-C: rc[7] static register cache + LDS
// counting-sort. D-phase: PAIR pipeline (depth 2 — depth 4 spilled under the
// 64-VGPR cap, round-5 FETCH_SIZE x12 regression).
// Prefetched ids CLAMPed to < N_NODES (pad garbage -> row 0, predicated off).
// ---------------------------------------------------------------------------
__global__ __launch_bounds__(1024, 8) void accum12_kernel(
    const unsigned* __restrict__ bins, const int* __restrict__ bin_cursor,
    const __half* __restrict__ rec,
    const float* __restrict__ att_src, const float* __restrict__ att_dst,
    const float* __restrict__ bias, const float* __restrict__ Wfc,
    const float* __restrict__ bfc, float* __restrict__ out)
{
    __shared__ unsigned staging[CAPB + 64];     // +64 pad: batch reads may run past cnt
    __shared__ int hist[RB], offs[RB + 1], cur[RB];

    int t = threadIdx.x;
    int b = blockIdx.x;
    int node0 = b * RB;

    if (t < RB) hist[t] = 0;
    __syncthreads();

    int cnt = bin_cursor[b * CUR_STRIDE];
    if (cnt > CAPB) cnt = CAPB;
    const unsigned* seg = bins + (size_t)b * CAPB;

    // cache segment in registers — STATIC indexing (7*1024 >= CAPB)
    unsigned rc[7];
    #pragma unroll
    for (int k = 0; k < 7; ++k) {
        int i = t + 1024 * k;
        rc[k] = (i < cnt) ? seg[i] : 0xFFFFFFFFu;
    }

    // A: per-node histogram
    #pragma unroll
    for (int k = 0; k < 7; ++k)
        if (rc[k] != 0xFFFFFFFFu) atomicAdd(&hist[rc[k] >> SBITS], 1);
    __syncthreads();

    // B: scan of 196 counters by wave 0 (lane l<49 owns nodes 4l..4l+3)
    if (t < 49) {
        int h0 = hist[4 * t], h1 = hist[4 * t + 1];
        int h2 = hist[4 * t + 2], h3 = hist[4 * t + 3];
        int v = h0 + h1 + h2 + h3;
        int inc = v;
        #pragma unroll
        for (int o = 1; o < 64; o <<= 1) {
            int u = __shfl_up(inc, o);
            if (t >= o) inc += u;
        }
        int ex = inc - v;
        offs[4 * t] = ex;     cur[4 * t] = ex;     ex += h0;
        offs[4 * t + 1] = ex; cur[4 * t + 1] = ex; ex += h1;
        offs[4 * t + 2] = ex; cur[4 * t + 2] = ex; ex += h2;
        offs[4 * t + 3] = ex; cur[4 * t + 3] = ex;
        if (t == 48) offs[RB] = inc;
    }
    __syncthreads();

    // C: sort src ids into per-node order in LDS
    #pragma unroll
    for (int k = 0; k < 7; ++k) {
        unsigned r = rc[k];
        if (r != 0xFFFFFFFFu) {
            int slot = atomicAdd(&cur[r >> SBITS], 1);
            staging[slot] = r & SMASK;
        }
    }
    __syncthreads();

    // D: wave-per-node gather, node-PAIR pipelined
    int wv = t >> 6, lane = t & 63;
    int h_id = lane & 7, e_off = lane >> 3;

    // lane constants: att coefficients (LOG2E folded), FC weights, biases
    float as0 = att_src[2 * h_id] * LOG2E, as1 = att_src[2 * h_id + 1] * LOG2E;
    float ad0 = att_dst[2 * h_id] * LOG2E, ad1 = att_dst[2 * h_id + 1] * LOG2E;
    float b0 = bias[2 * h_id], b1 = bias[2 * h_id + 1];
    float w00 = Wfc[(2 * h_id) * 2 + 0],     w01 = Wfc[(2 * h_id) * 2 + 1];
    float w10 = Wfc[(2 * h_id + 1) * 2 + 0], w11 = Wfc[(2 * h_id + 1) * 2 + 1];
    float c0 = bfc[0], c1 = bfc[1];

    const __half2* recp = (const __half2*)rec;   // row n at index n*8 + h_id

    // clamp prefetched id into the rec table (pad garbage -> node 0)
    #define CLAMP(s) ((s) < (unsigned)N_NODES ? (s) : 0u)
    #define EDGE(rh, pred, adst, den, num0, num1) { \
        float h0_ = __half2float((rh).x), h1_ = __half2float((rh).y); \
        float l_ = fmaf(as0, h0_, fmaf(as1, h1_, adst)); \
        l_ = l_ > 0.f ? l_ : NEG_SLOPE * l_; \
        float p_ = (pred) ? exp2f(l_) : 0.f; \
        den += p_; num0 = fmaf(p_, h0_, num0); num1 = fmaf(p_, h1_, num1); }

    // node slots: ln = wv + 16*k for k = 0..12 (196/16 = 12.25); guard ln<RB
    for (int k = 0; k < 13; k += 2) {
        int lnA = wv + 16 * k, lnB = lnA + 16;
        bool vA = lnA < RB, vB = lnB < RB;
        int nA = node0 + lnA, nB = node0 + lnB;
        vA = vA && (nA < N_NODES);
        vB = vB && (nB < N_NODES);
        if (!vA) break;          // slots are monotone: if A invalid, B is too

        int stA = offs[lnA], degA = offs[lnA + 1] - stA;
        int stB = vB ? offs[lnB] : 0;
        int degB = vB ? (offs[lnB + 1] - stB) : 0;

        // ---- issue phase: ALL of A's and B's loads before any compute ----
        int iA = stA + e_off, iB = stB + e_off;
        unsigned sA0 = CLAMP(staging[iA]);
        unsigned sA1 = CLAMP(staging[iA + 8]);
        unsigned sA2 = CLAMP(staging[iA + 16]);
        unsigned sA3 = CLAMP(staging[iA + 24]);
        unsigned sB0 = CLAMP(staging[iB]);
        unsigned sB1 = CLAMP(staging[iB + 8]);
        unsigned sB2 = CLAMP(staging[iB + 16]);
        unsigned sB3 = CLAMP(staging[iB + 24]);

        __half2 hnA = recp[(size_t)nA * 8 + h_id];
        __half2 hnB = recp[(size_t)(vB ? nB : nA) * 8 + h_id];

        __half2 rA0 = recp[(size_t)sA0 * 8 + h_id];
        __half2 rA1 = recp[(size_t)sA1 * 8 + h_id];
        __half2 rA2 = recp[(size_t)sA2 * 8 + h_id];
        __half2 rA3 = recp[(size_t)sA3 * 8 + h_id];
        __half2 rB0 = recp[(size_t)sB0 * 8 + h_id];
        __half2 rB1 = recp[(size_t)sB1 * 8 + h_id];
        __half2 rB2 = recp[(size_t)sB2 * 8 + h_id];
        __half2 rB3 = recp[(size_t)sB3 * 8 + h_id];

        // ---- node A compute (covers B's loads in flight) ----
        float hnA0 = __half2float(hnA.x), hnA1 = __half2float(hnA.y);
        float adstA = fmaf(ad0, hnA0, ad1 * hnA1);
        float denA = 0.f, n0A = 0.f, n1A = 0.f;
        EDGE(rA0, e_off      < degA, adstA, denA, n0A, n1A);
        EDGE(rA1, e_off + 8  < degA, adstA, denA, n0A, n1A);
        EDGE(rA2, e_off + 16 < degA, adstA, denA, n0A, n1A);
        EDGE(rA3, e_off + 24 < degA, adstA, denA, n0A, n1A);

        // ---- node B compute ----
        float hnB0 = __half2float(hnB.x), hnB1 = __half2float(hnB.y);
        float adstB = fmaf(ad0, hnB0, ad1 * hnB1);
        float denB = 0.f, n0B = 0.f, n1B = 0.f;
        EDGE(rB0, e_off      < degB, adstB, denB, n0B, n1B);
        EDGE(rB1, e_off + 8  < degB, adstB, denB, n0B, n1B);
        EDGE(rB2, e_off + 16 < degB, adstB, denB, n0B, n1B);
        EDGE(rB3, e_off + 24 < degB, adstB, denB, n0B, n1B);

        // ---- interleaved tails (deg > 32): A and B loads alternate ----
        if (degA > 32 || degB > 32) {
            for (int i = 32 + e_off; i < degA || i < degB; i += 8) {
                bool ta = i < degA, tb = i < degB;
                unsigned sa = ta ? staging[stA + i] : 0u;   // valid entries already masked
                unsigned sb = tb ? staging[stB + i] : 0u;
                __half2 ra = recp[(size_t)sa * 8 + h_id];
                __half2 rb = recp[(size_t)sb * 8 + h_id];
                EDGE(ra, ta, adstA, denA, n0A, n1A);
                EDGE(rb, tb, adstB, denB, n0B, n1B);
            }
        }

        // ---- reductions (A and B independent -> ILP) ----
        #pragma unroll
        for (int m = 8; m < 64; m <<= 1) {
            denA += __shfl_xor(denA, m);
            n0A  += __shfl_xor(n0A, m);
            n1A  += __shfl_xor(n1A, m);
            denB += __shfl_xor(denB, m);
            n0B  += __shfl_xor(n0B, m);
            n1B  += __shfl_xor(n1B, m);
        }
        // self-loops folded analytically
        {
            float l = fmaf(as0, hnA0, fmaf(as1, hnA1, adstA));
            l = l > 0.f ? l : NEG_SLOPE * l;
            float p = exp2f(l);
            denA += p; n0A = fmaf(p, hnA0, n0A); n1A = fmaf(p, hnA1, n1A);
        }
        {
            float l = fmaf(as0, hnB0, fmaf(as1, hnB1, adstB));
            l = l > 0.f ? l : NEG_SLOPE * l;
            float p = exp2f(l);
            denB += p; n0B = fmaf(p, hnB0, n0B); n1B = fmaf(p, hnB1, n1B);
        }
        // normalize + bias + FC, sum over heads — node A
        {
            float inv = 1.f / denA;
            float g0 = fmaf(n0A, inv, b0);
            float g1 = fmaf(n1A, inv, b1);
            float o0 = g0 * w00 + g1 * w10;
            float o1 = g0 * w01 + g1 * w11;
            #pragma unroll
            for (int m = 1; m < 8; m <<= 1) {
                o0 += __shfl_xor(o0, m);
                o1 += __shfl_xor(o1, m);
            }
            if (lane == 0) {
                float2 res = { o0 + c0, o1 + c1 };
                *(float2*)(out + (size_t)nA * 2) = res;
            }
        }
        // node B
        if (vB) {
            float inv = 1.f / denB;
            float g0 = fmaf(n0B, inv, b0);
            float g1 = fmaf(n1B, inv, b1);
            float o0 = g0 * w00 + g1 * w10;
            float o1 = g0 * w01 + g1 * w11;
            #pragma unroll
            for (int m = 1; m < 8; m <<= 1) {
                o0 += __shfl_xor(o0, m);
                o1 += __shfl_xor(o1, m);
            }
            if (lane == 0) {
                float2 res = { o0 + c0, o1 + c1 };
                *(float2*)(out + (size_t)nB * 2) = res;
            }
        }
    }
    #undef EDGE
    #undef CLAMP
}

// ---------------------------------------------------------------------------
extern "C" void kernel_launch(void* const* d_in, const int* in_sizes, int n_in,
                              void* d_out, int out_size, void* d_ws, size_t ws_size,
                              hipStream_t stream)
{
    const float* x       = (const float*)d_in[0];
    const int*   ei      = (const int*)d_in[1];   // [2, E]
    const float* W       = (const float*)d_in[3];
    const float* att_src = (const float*)d_in[4];
    const float* att_dst = (const float*)d_in[5];
    const float* bias    = (const float*)d_in[6];
    const float* Wfc     = (const float*)d_in[7];
    const float* bfc     = (const float*)d_in[8];
    float*       out     = (float*)d_out;

    const int E  = in_sizes[1] / 2;
    const int SB = (E + BIN_C - 1) / BIN_C;            // bin-role blocks (782)
    const int PB = (N_NODES * 8 + 511) / 512;          // phase1-role blocks (1563)

    // ws layout: rec f16[N*16] (3.2MB) | bin_cursor i32[NB*16] (32KB, 64B/line)
    //            | (4KB align) | bins u32[NB*CAPB] (14.39MB)
    __half* rec        = (__half*)d_ws;
    int*    bin_cursor = (int*)((char*)d_ws + (size_t)N_NODES * NF * 2);
    size_t  bins_off   = (((size_t)((char*)bin_cursor - (char*)d_ws)) + (size_t)NB * CUR_STRIDE * 4 + 4095) & ~(size_t)4095;
    unsigned* bins     = (unsigned*)((char*)d_ws + bins_off);

    hipMemsetAsync(bin_cursor, 0, (size_t)NB * CUR_STRIDE * sizeof(int), stream);

    fused_p1_bin<<<SB + PB, 512, 0, stream>>>(
        ei, bin_cursor, bins, x, W, rec, E, SB);
    accum12_kernel<<<NB, 1024, 0, stream>>>(
        bins, bin_cursor, rec, att_src, att_dst, bias, Wfc, bfc, out);
}

// Round 9
// 182.438 us; speedup vs baseline: 1.0317x; 1.0317x over previous
//
// Round 9 = round 8 resubmission (round 8 failed on infra: container died twice,
// no kernel signal). No code changes — preserves the A/B against round 7.
#include <hip/hip_runtime.h>
#include <hip/hip_fp16.h>

#define N_NODES 100000
#define IN_F 128
#define NF 16      // HEADS * OUT_C
#define HEADS 8
#define NEG_SLOPE 0.2f
#define LOG2E 1.44269504f

#define RB 196          // nodes per bin (NON-pow2: NB=511 ~= 2 blocks/CU exactly)
#define NB 511          // ceil(100000/196); 510*196=99960, bin 510 has 40 nodes
#define SBITS 17        // src id bits (100000 < 2^17)
#define SMASK ((1u << SBITS) - 1)
#define BIN_C 4096      // edges per binning block (8/thread @512)
#define CAPB 7040       // per-bin capacity: mean 6272 + 9.7 sigma; rc[7] covers it
#define CUR_STRIDE 16   // bin_cursor padded to 1 per 64B cache line

#define PB_BLOCKS 196   // phase1 blocks: 196 x 512 nodes = 100352 >= N_NODES

// Node record rec[n]: 16 halves = 32B. Table = 3.2 MB -> L2-resident per XCD.

typedef _Float16 f16x8 __attribute__((ext_vector_type(8)));
typedef float    f32x4 __attribute__((ext_vector_type(4)));

// ---------------------------------------------------------------------------
// phase1 (MFMA): h = x@W as [16x128]@[128x16] tiles via mfma_f32_16x16x32_f16.
// One wave computes 16 nodes per 4-MFMA chain. x read EXACTLY ONCE (16 rows x
// 64B per wave-load, line-aligned — kills the old 8x redundant row reads);
// W lives in 4 B-fragments (16 VGPR), loaded once per wave; NO LDS.
// Fragment layout (m89/m156): A: row=lane&15, k=4*(lane>>4)+e, elems 4..7 at
// k+16; B symmetric (col=lane&15); D: col=lane&15, row=4*(lane>>4)+reg.
// fp16 inputs + fp32 accum: h error ~1e-3 << 0.0395 threshold (rec is fp16).
// ---------------------------------------------------------------------------
__device__ __forceinline__ void phase1_mfma(
    int pb, const float* __restrict__ x, const float* __restrict__ W,
    __half* __restrict__ rec)
{
    int t = threadIdx.x;
    int lane = t & 63, wv = t >> 6;
    int r16 = lane & 15, g = lane >> 4;      // g = 0..3

    // B-frags (W [128][16] row-major): b[kk] elems e: W[32kk+4g+e][r16],
    // elems e+4: W[32kk+16+4g+e][r16]. Loaded once, reused for all tiles.
    f16x8 bw[4];
    const float* wb = W + (4 * g) * 16 + r16;
    #pragma unroll
    for (int kk = 0; kk < 4; ++kk) {
        #pragma unroll
        for (int e = 0; e < 4; ++e) {
            bw[kk][e]     = (_Float16)wb[(32 * kk + e) * 16];
            bw[kk][e + 4] = (_Float16)wb[(32 * kk + 16 + e) * 16];
        }
    }

    int base = pb * 512 + wv * 64;           // this wave's first node
    #pragma unroll
    for (int tile = 0; tile < 4; ++tile) {
        int n0 = base + tile * 16;
        if (n0 >= N_NODES) break;            // wave-uniform
        int nr = n0 + r16;
        const float* xr = x + (size_t)(nr < N_NODES ? nr : N_NODES - 1) * IN_F + 4 * g;

        f32x4 acc = {0.f, 0.f, 0.f, 0.f};
        #pragma unroll
        for (int kk = 0; kk < 4; ++kk) {
            float4 xlo = *(const float4*)(xr + 32 * kk);        // k = 32kk+4g+0..3
            float4 xhi = *(const float4*)(xr + 32 * kk + 16);   // k = 32kk+16+4g+0..3
            f16x8 a;
            a[0] = (_Float16)xlo.x; a[1] = (_Float16)xlo.y;
            a[2] = (_Float16)xlo.z; a[3] = (_Float16)xlo.w;
            a[4] = (_Float16)xhi.x; a[5] = (_Float16)xhi.y;
            a[6] = (_Float16)xhi.z; a[7] = (_Float16)xhi.w;
            acc = __builtin_amdgcn_mfma_f32_16x16x32_f16(a, bw[kk], acc, 0, 0, 0);
        }
        // D: lane holds h[node = n0 + 4g + e][col = r16], e = 0..3
        #pragma unroll
        for (int e = 0; e < 4; ++e) {
            int n = n0 + 4 * g + e;
            if (n < N_NODES)
                rec[(size_t)n * NF + r16] = __float2half(acc[e]);
        }
    }
}

// ---------------------------------------------------------------------------
// Fused kernel: 980 blocks; idx%5==4 -> phase1-MFMA (196), else bin (784,
// last 2 no-ops). Bin role: load 4096 edges into registers; LDS counting-sort
// by dst bin (511 bins of 196 nodes, d/196 magic-mul); reserve per-(block,bin)
// ranges with one global atomic each (line-padded cursors); write packed
// (d_local<<17 | src).
// ---------------------------------------------------------------------------
__global__ __launch_bounds__(512) void fused_p1_bin(
    const int* __restrict__ ei, int* __restrict__ bin_cursor,
    unsigned* __restrict__ bins,
    const float* __restrict__ x, const float* __restrict__ W,
    __half* __restrict__ rec, int E)
{
    __shared__ struct {
        unsigned staging[BIN_C];        // 16 KB
        unsigned short bin16[BIN_C];    // 8 KB
        int hist[NB], offs[NB], cur[NB], gbase[NB]; // 8.2 KB
        int wsum[8], woff[8];
    } sm;

    int idx = blockIdx.x;
    if (idx % 5 == 4) {                  // phase1 role
        phase1_mfma(idx / 5, x, W, rec);
        return;
    }
    int bin_id = idx - (idx + 1) / 5;    // 0..783

    int t = threadIdx.x;
    int base = bin_id * BIN_C;
    int n_valid = E - base;
    if (n_valid > BIN_C) n_valid = BIN_C;
    if (n_valid < 0) n_valid = 0;

    // load this block's edges once, coalesced, into registers
    int es[8], ed[8];
    #pragma unroll
    for (int k = 0; k < 8; ++k) {
        int i = t + 512 * k;
        bool v = i < n_valid;
        es[k] = v ? ei[base + i] : 0;
        ed[k] = v ? ei[E + base + i] : -1;
    }

    if (t < NB) sm.hist[t] = 0;
    __syncthreads();

    // A: histogram of dst bins (from registers); bin = d/196 (magic-mul)
    #pragma unroll
    for (int k = 0; k < 8; ++k)
        if (ed[k] >= 0) atomicAdd(&sm.hist[(unsigned)ed[k] / RB], 1);
    __syncthreads();

    // B: block-wide exclusive scan of hist (1 bin/thread) + global reserve
    int sum = (t < NB) ? sm.hist[t] : 0;
    int lane = t & 63, wid = t >> 6;
    int v = sum;
    #pragma unroll
    for (int o = 1; o < 64; o <<= 1) {
        int u = __shfl_up(v, o);
        if (lane >= o) v += u;
    }
    if (lane == 63) sm.wsum[wid] = v;
    __syncthreads();
    if (t == 0) { int r = 0; for (int w = 0; w < 8; ++w) { sm.woff[w] = r; r += sm.wsum[w]; } }
    __syncthreads();
    int run = sm.woff[wid] + v - sum;
    if (t < NB) { sm.offs[t] = run; sm.cur[t] = run; }
    __syncthreads();
    if (t < NB)
        sm.gbase[t] = sm.hist[t] ? atomicAdd(&bin_cursor[t * CUR_STRIDE], sm.hist[t]) : 0;
    __syncthreads();

    // C: counting-sort into LDS staging (from registers)
    #pragma unroll
    for (int k = 0; k < 8; ++k) {
        if (ed[k] >= 0) {
            unsigned d = (unsigned)ed[k];
            unsigned bb = d / RB;
            unsigned dl = d - bb * RB;          // local node id, 0..195
            int slot = atomicAdd(&sm.cur[bb], 1);
            sm.staging[slot] = (dl << SBITS) | (unsigned)es[k];
            sm.bin16[slot] = (unsigned short)bb;
        }
    }
    __syncthreads();

    // D: coalesced write-out (runs of ~8 consecutive slots per bin)
    for (int i = t; i < n_valid; i += 512) {
        int b = sm.bin16[i];
        int pos = sm.gbase[b] + (i - sm.offs[b]);
        if (pos < CAPB) bins[(size_t)b * CAPB + pos] = sm.staging[i];
    }
}

// ---------------------------------------------------------------------------
// Accum: ONE 1024-thread block per 196-node bin, grid 511 = 255 CUs x 2 + 1
// -> ~100% CU balance. Phases A-C: rc[7] static register cache + LDS
// counting-sort. D-phase: PAIR pipeline (depth 2 — depth 4 spilled under the
// 64-VGPR cap, round-5 FETCH_SIZE x12 regression).
// Prefetched ids CLAMPed to < N_NODES (pad garbage -> row 0, predicated off).
// ---------------------------------------------------------------------------
__global__ __launch_bounds__(1024, 8) void accum12_kernel(
    const unsigned* __restrict__ bins, const int* __restrict__ bin_cursor,
    const __half* __restrict__ rec,
    const float* __restrict__ att_src, const float* __restrict__ att_dst,
    const float* __restrict__ bias, const float* __restrict__ Wfc,
    const float* __restrict__ bfc, float* __restrict__ out)
{
    __shared__ unsigned staging[CAPB + 64];     // +64 pad: batch reads may run past cnt
    __shared__ int hist[RB], offs[RB + 1], cur[RB];

    int t = threadIdx.x;
    int b = blockIdx.x;
    int node0 = b * RB;

    if (t < RB) hist[t] = 0;
    __syncthreads();

    int cnt = bin_cursor[b * CUR_STRIDE];
    if (cnt > CAPB) cnt = CAPB;
    const unsigned* seg = bins + (size_t)b * CAPB;

    // cache segment in registers — STATIC indexing (7*1024 >= CAPB)
    unsigned rc[7];
    #pragma unroll
    for (int k = 0; k < 7; ++k) {
        int i = t + 1024 * k;
        rc[k] = (i < cnt) ? seg[i] : 0xFFFFFFFFu;
    }

    // A: per-node histogram
    #pragma unroll
    for (int k = 0; k < 7; ++k)
        if (rc[k] != 0xFFFFFFFFu) atomicAdd(&hist[rc[k] >> SBITS], 1);
    __syncthreads();

    // B: scan of 196 counters by wave 0 (lane l<49 owns nodes 4l..4l+3)
    if (t < 49) {
        int h0 = hist[4 * t], h1 = hist[4 * t + 1];
        int h2 = hist[4 * t + 2], h3 = hist[4 * t + 3];
        int v = h0 + h1 + h2 + h3;
        int inc = v;
        #pragma unroll
        for (int o = 1; o < 64; o <<= 1) {
            int u = __shfl_up(inc, o);
            if (t >= o) inc += u;
        }
        int ex = inc - v;
        offs[4 * t] = ex;     cur[4 * t] = ex;     ex += h0;
        offs[4 * t + 1] = ex; cur[4 * t + 1] = ex; ex += h1;
        offs[4 * t + 2] = ex; cur[4 * t + 2] = ex; ex += h2;
        offs[4 * t + 3] = ex; cur[4 * t + 3] = ex;
        if (t == 48) offs[RB] = inc;
    }
    __syncthreads();

    // C: sort src ids into per-node order in LDS
    #pragma unroll
    for (int k = 0; k < 7; ++k) {
        unsigned r = rc[k];
        if (r != 0xFFFFFFFFu) {
            int slot = atomicAdd(&cur[r >> SBITS], 1);
            staging[slot] = r & SMASK;
        }
    }
    __syncthreads();

    // D: wave-per-node gather, node-PAIR pipelined
    int wv = t >> 6, lane = t & 63;
    int h_id = lane & 7, e_off = lane >> 3;

    // lane constants: att coefficients (LOG2E folded), FC weights, biases
    float as0 = att_src[2 * h_id] * LOG2E, as1 = att_src[2 * h_id + 1] * LOG2E;
    float ad0 = att_dst[2 * h_id] * LOG2E, ad1 = att_dst[2 * h_id + 1] * LOG2E;
    float b0 = bias[2 * h_id], b1 = bias[2 * h_id + 1];
    float w00 = Wfc[(2 * h_id) * 2 + 0],     w01 = Wfc[(2 * h_id) * 2 + 1];
    float w10 = Wfc[(2 * h_id + 1) * 2 + 0], w11 = Wfc[(2 * h_id + 1) * 2 + 1];
    float c0 = bfc[0], c1 = bfc[1];

    const __half2* recp = (const __half2*)rec;   // row n at index n*8 + h_id

    // clamp prefetched id into the rec table (pad garbage -> node 0)
    #define CLAMP(s) ((s) < (unsigned)N_NODES ? (s) : 0u)
    #define EDGE(rh, pred, adst, den, num0, num1) { \
        float h0_ = __half2float((rh).x), h1_ = __half2float((rh).y); \
        float l_ = fmaf(as0, h0_, fmaf(as1, h1_, adst)); \
        l_ = l_ > 0.f ? l_ : NEG_SLOPE * l_; \
        float p_ = (pred) ? exp2f(l_) : 0.f; \
        den += p_; num0 = fmaf(p_, h0_, num0); num1 = fmaf(p_, h1_, num1); }

    // node slots: ln = wv + 16*k for k = 0..12 (196/16 = 12.25); guard ln<RB
    for (int k = 0; k < 13; k += 2) {
        int lnA = wv + 16 * k, lnB = lnA + 16;
        bool vA = lnA < RB, vB = lnB < RB;
        int nA = node0 + lnA, nB = node0 + lnB;
        vA = vA && (nA < N_NODES);
        vB = vB && (nB < N_NODES);
        if (!vA) break;          // slots are monotone: if A invalid, B is too

        int stA = offs[lnA], degA = offs[lnA + 1] - stA;
        int stB = vB ? offs[lnB] : 0;
        int degB = vB ? (offs[lnB + 1] - stB) : 0;

        // ---- issue phase: ALL of A's and B's loads before any compute ----
        int iA = stA + e_off, iB = stB + e_off;
        unsigned sA0 = CLAMP(staging[iA]);
        unsigned sA1 = CLAMP(staging[iA + 8]);
        unsigned sA2 = CLAMP(staging[iA + 16]);
        unsigned sA3 = CLAMP(staging[iA + 24]);
        unsigned sB0 = CLAMP(staging[iB]);
        unsigned sB1 = CLAMP(staging[iB + 8]);
        unsigned sB2 = CLAMP(staging[iB + 16]);
        unsigned sB3 = CLAMP(staging[iB + 24]);

        __half2 hnA = recp[(size_t)nA * 8 + h_id];
        __half2 hnB = recp[(size_t)(vB ? nB : nA) * 8 + h_id];

        __half2 rA0 = recp[(size_t)sA0 * 8 + h_id];
        __half2 rA1 = recp[(size_t)sA1 * 8 + h_id];
        __half2 rA2 = recp[(size_t)sA2 * 8 + h_id];
        __half2 rA3 = recp[(size_t)sA3 * 8 + h_id];
        __half2 rB0 = recp[(size_t)sB0 * 8 + h_id];
        __half2 rB1 = recp[(size_t)sB1 * 8 + h_id];
        __half2 rB2 = recp[(size_t)sB2 * 8 + h_id];
        __half2 rB3 = recp[(size_t)sB3 * 8 + h_id];

        // ---- node A compute (covers B's loads in flight) ----
        float hnA0 = __half2float(hnA.x), hnA1 = __half2float(hnA.y);
        float adstA = fmaf(ad0, hnA0, ad1 * hnA1);
        float denA = 0.f, n0A = 0.f, n1A = 0.f;
        EDGE(rA0, e_off      < degA, adstA, denA, n0A, n1A);
        EDGE(rA1, e_off + 8  < degA, adstA, denA, n0A, n1A);
        EDGE(rA2, e_off + 16 < degA, adstA, denA, n0A, n1A);
        EDGE(rA3, e_off + 24 < degA, adstA, denA, n0A, n1A);

        // ---- node B compute ----
        float hnB0 = __half2float(hnB.x), hnB1 = __half2float(hnB.y);
        float adstB = fmaf(ad0, hnB0, ad1 * hnB1);
        float denB = 0.f, n0B = 0.f, n1B = 0.f;
        EDGE(rB0, e_off      < degB, adstB, denB, n0B, n1B);
        EDGE(rB1, e_off + 8  < degB, adstB, denB, n0B, n1B);
        EDGE(rB2, e_off + 16 < degB, adstB, denB, n0B, n1B);
        EDGE(rB3, e_off + 24 < degB, adstB, denB, n0B, n1B);

        // ---- interleaved tails (deg > 32): A and B loads alternate ----
        if (degA > 32 || degB > 32) {
            for (int i = 32 + e_off; i < degA || i < degB; i += 8) {
                bool ta = i < degA, tb = i < degB;
                unsigned sa = ta ? staging[stA + i] : 0u;   // valid entries already masked
                unsigned sb = tb ? staging[stB + i] : 0u;
                __half2 ra = recp[(size_t)sa * 8 + h_id];
                __half2 rb = recp[(size_t)sb * 8 + h_id];
                EDGE(ra, ta, adstA, denA, n0A, n1A);
                EDGE(rb, tb, adstB, denB, n0B, n1B);
            }
        }

        // ---- reductions (A and B independent -> ILP) ----
        #pragma unroll
        for (int m = 8; m < 64; m <<= 1) {
            denA += __shfl_xor(denA, m);
            n0A  += __shfl_xor(n0A, m);
            n1A  += __shfl_xor(n1A, m);
            denB += __shfl_xor(denB, m);
            n0B  += __shfl_xor(n0B, m);
            n1B  += __shfl_xor(n1B, m);
        }
        // self-loops folded analytically
        {
            float l = fmaf(as0, hnA0, fmaf(as1, hnA1, adstA));
            l = l > 0.f ? l : NEG_SLOPE * l;
            float p = exp2f(l);
            denA += p; n0A = fmaf(p, hnA0, n0A); n1A = fmaf(p, hnA1, n1A);
        }
        {
            float l = fmaf(as0, hnB0, fmaf(as1, hnB1, adstB));
            l = l > 0.f ? l : NEG_SLOPE * l;
            float p = exp2f(l);
            denB += p; n0B = fmaf(p, hnB0, n0B); n1B = fmaf(p, hnB1, n1B);
        }
        // normalize + bias + FC, sum over heads — node A
        {
            float inv = 1.f / denA;
            float g0 = fmaf(n0A, inv, b0);
            float g1 = fmaf(n1A, inv, b1);
            float o0 = g0 * w00 + g1 * w10;
            float o1 = g0 * w01 + g1 * w11;
            #pragma unroll
            for (int m = 1; m < 8; m <<= 1) {
                o0 += __shfl_xor(o0, m);
                o1 += __shfl_xor(o1, m);
            }
            if (lane == 0) {
                float2 res = { o0 + c0, o1 + c1 };
                *(float2*)(out + (size_t)nA * 2) = res;
            }
        }
        // node B
        if (vB) {
            float inv = 1.f / denB;
            float g0 = fmaf(n0B, inv, b0);
            float g1 = fmaf(n1B, inv, b1);
            float o0 = g0 * w00 + g1 * w10;
            float o1 = g0 * w01 + g1 * w11;
            #pragma unroll
            for (int m = 1; m < 8; m <<= 1) {
                o0 += __shfl_xor(o0, m);
                o1 += __shfl_xor(o1, m);
            }
            if (lane == 0) {
                float2 res = { o0 + c0, o1 + c1 };
                *(float2*)(out + (size_t)nB * 2) = res;
            }
        }
    }
    #undef EDGE
    #undef CLAMP
}

// ---------------------------------------------------------------------------
extern "C" void kernel_launch(void* const* d_in, const int* in_sizes, int n_in,
                              void* d_out, int out_size, void* d_ws, size_t ws_size,
                              hipStream_t stream)
{
    const float* x       = (const float*)d_in[0];
    const int*   ei      = (const int*)d_in[1];   // [2, E]
    const float* W       = (const float*)d_in[3];
    const float* att_src = (const float*)d_in[4];
    const float* att_dst = (const float*)d_in[5];
    const float* bias    = (const float*)d_in[6];
    const float* Wfc     = (const float*)d_in[7];
    const float* bfc     = (const float*)d_in[8];
    float*       out     = (float*)d_out;

    const int E  = in_sizes[1] / 2;

    // grid: 980 blocks; idx%5==4 -> phase1 (196), else bin (784, last 2 no-op)
    const int GRID = 980;

    // ws layout: rec f16[N*16] (3.2MB) | bin_cursor i32[NB*16] (32KB, 64B/line)
    //            | (4KB align) | bins u32[NB*CAPB] (14.39MB)
    __half* rec        = (__half*)d_ws;
    int*    bin_cursor = (int*)((char*)d_ws + (size_t)N_NODES * NF * 2);
    size_t  bins_off   = (((size_t)((char*)bin_cursor - (char*)d_ws)) + (size_t)NB * CUR_STRIDE * 4 + 4095) & ~(size_t)4095;
    unsigned* bins     = (unsigned*)((char*)d_ws + bins_off);

    hipMemsetAsync(bin_cursor, 0, (size_t)NB * CUR_STRIDE * sizeof(int), stream);

    fused_p1_bin<<<GRID, 512, 0, stream>>>(
        ei, bin_cursor, bins, x, W, rec, E);
    accum12_kernel<<<NB, 1024, 0, stream>>>(
        bins, bin_cursor, rec, att_src, att_dst, bias, Wfc, bfc, out);
}